// Round 18
// baseline (122.618 us; speedup 1.0000x reference)
//
#include <hip/hip_runtime.h>
#include <math.h>

#define T 32
#define K 2048
#define NBLOCKS 256
#define NTHREADS 512
#define HB 128                          // blocks per direction
#define CPB 16                          // columns per block (2 per wave)
#define QS 4                            // K / NTHREADS slots per thread
#define SSTRIDE 32                      // ints: 128 B -> one MALL line per sentinel
#define L2E_F 1.4426950408889634f       // log2(e)
#define LN2_F 0.6931471805599453f
#define LOG2PI_F 1.8378770664093453f
#define SP_F     0.17677669529663687f   // sqrt(1/32)
#define LOG_SP_F (-1.7328679513998633f) // ln(sqrt(1/32))
#define CNORM_F  (-(LOG_SP_F) - 0.5f * LOG2PI_F)   // -ln(sp) - 0.5 ln2pi

#if __has_builtin(__builtin_amdgcn_exp2f)
#define EXP2F(x) __builtin_amdgcn_exp2f(x)
#else
#define EXP2F(x) exp2f(x)
#endif
#if __has_builtin(__builtin_amdgcn_logf)
#define LOG2F(x) __builtin_amdgcn_logf(x)
#else
#define LOG2F(x) log2f(x)
#endif

// ALL global sync traffic is relaxed agent-scope atomics (write-through to
// the MALL, bypassing non-coherent per-XCD L2s). NO agent-scope
// release/acquire anywhere (R2/R7: ~15us/step of L2 cache maintenance).
__device__ __forceinline__ float aload4(const float* p) {
    return __hip_atomic_load(p, __ATOMIC_RELAXED, __HIP_MEMORY_SCOPE_AGENT);
}
__device__ __forceinline__ void astore4(float* p, float v) {
    __hip_atomic_store(p, v, __ATOMIC_RELAXED, __HIP_MEMORY_SCOPE_AGENT);
}
__device__ __forceinline__ int sload(const int* p) {
    return __hip_atomic_load(p, __ATOMIC_RELAXED, __HIP_MEMORY_SCOPE_AGENT);
}
__device__ __forceinline__ void sstore(int* p, int v) {
    __hip_atomic_store(p, v, __ATOMIC_RELAXED, __HIP_MEMORY_SCOPE_AGENT);
}

// R15's champion (61.7us) with ONE change: barrier B is GONE. After its
// publish, each wave drains its own stores (s_waitcnt vmcnt(0) — the same
// visibility guarantee barrier B's pre-s_barrier drain provided, minus the
// 8-wave rendezvous), lane 0 bumps a monotonic LDS counter (ACQ_REL,
// workgroup scope = lgkmcnt-only), and the 8th-arriving wave fires the
// block sentinel. Early waves run ahead into the next step's eps loads and
// detection immediately.
//   Ordering: every wave's publish is vmcnt-drained before its LDS inc; the
// ACQ_REL inc chain orders all 8 drained publishes before the 8th wave's
// sentinel store. LDS parity reuse: a wave writes shzD[par] at step p+2
// only after detecting own-block sentinel >= p+3, which requires all own
// waves published step p+1, hence finished step p's shzD[par] reads
// (program order) — hazard closed without the barrier.
// Everything else identical to R15: bidirectional meet-in-the-middle
// (16 fwd / 15 bwd steps), 512 thr / 128 blk per direction, 2 cols/wave,
// spread one-line sentinels (R15: packed hot lines serialize at the MALL),
// ONE polling wave + LDS-flag handoff, one-shot 4B row reads, barrier A
// before compute, log2-domain chain state, signed sentinels (0xAA poison
// is negative, never satisfies >=).
__global__ __launch_bounds__(NTHREADS) void fused_kernel(
    const float* __restrict__ means, const float* __restrict__ log_stds,
    const float* __restrict__ eps, float* __restrict__ fbuf,
    float* __restrict__ bbuf, int* __restrict__ fsent, int* __restrict__ bsent,
    float* __restrict__ out)
{
    __shared__ float2 shzD[2][K];    // 32 KB: (z_j, D_j) staging, parity dbuf
    __shared__ float2 lzc[T][CPB];   // own cols: (32*L2E*z, cm2 const)
    __shared__ float smu[T], sstd[T], slq2[T];
    __shared__ float red[NTHREADS];
    __shared__ int ldsflag;
    __shared__ int pubcnt[2];

    const int tid  = threadIdx.x;
    const int b    = blockIdx.x;
    const bool fwd = (b < HB);
    const int lb   = fwd ? b : b - HB;
    const int col0 = lb * CPB;

    if (tid == 0) { ldsflag = 0; pubcnt[0] = 0; pubcnt[1] = 0; }

    // ---- setup: thread (t = tid>>4, dcol = tid&15) handles (t, col0+dcol) ----
    {
        int t = tid >> 4, dcol = tid & 15;
        float mu = means[t];
        float st = expf(log_stds[t]);
        if (dcol == 0) {
            smu[t] = mu; sstd[t] = st;
            slq2[t] = L2E_F * (logf(st) + 0.5f * LOG2PI_F);
        }
        float e = eps[t * K + col0 + dcol];
        float z = fmaf(st, e, mu);
        // (z-mu)/st == e exactly: log_q = -0.5 e^2 - ln(st) - 0.5 ln2pi
        float log_q = fmaf(-0.5f * e, e, -logf(st) - 0.5f * LOG2PI_F);
        float tz2 = (32.0f * L2E_F) * z;
        if (fwd) {
            float cm2 = fmaf((-16.0f * L2E_F) * z, z,
                             L2E_F * (CNORM_F - log_q)) - 11.0f;   // log2K = 11
            lzc[t][dcol] = make_float2(tz2, cm2);
            if (t == 0) {   // seed r_0, parity 0
                float r0 = fmaf(-16.0f * z, z, CNORM_F) - log_q;
                astore4(&fbuf[col0 + dcol], r0 * L2E_F);
            }
        } else {
            float cm2 = fmaf((-16.0f * L2E_F) * z, z, L2E_F * CNORM_F) - 11.0f;
            lzc[t][dcol] = make_float2(tz2, cm2);
            if (t == T - 1) {   // seed c_31 = likelihood, parity 0
                float d = 0.5f - z;
                float c31 = fmaf(-0.5f * d, d, -0.5f * LOG2PI_F);
                astore4(&bbuf[col0 + dcol], c31 * L2E_F);
            }
        }
    }
    __syncthreads();               // drains seed stores (vmcnt) + LDS init
    int* mysent = fwd ? fsent : bsent;
    if (tid == 0) sstore(&mysent[lb * SSTRIDE], 1);

    const int lane = tid & 63;
    const int wave = tid >> 6;     // 0..7: columns 2w, 2w+1
    float* mybuf = fwd ? fbuf : bbuf;
    const int nstep = fwd ? 16 : 15;

    for (int p = 0; p < nstep; ++p) {
        const int par  = p & 1;
        const int need = p + 1;
        const int tin  = fwd ? p : 31 - p;
        const int town = fwd ? p + 1 : 30 - p;
        const float mu_i  = smu[tin];
        const float std_i = sstd[tin];
        const float lqc   = slq2[tin];
        const float* erow = eps + tin * K;

        // ---- pre-poll: z + D-addend for own QS slots (r-independent) ----
        float zloc[QS], dadd[QS];
        #pragma unroll
        for (int q = 0; q < QS; ++q) {
            float e = erow[tid + q * NTHREADS];
            float z = fmaf(std_i, e, mu_i);
            zloc[q] = z;
            float base = fwd ? 0.0f : fmaf((0.5f * L2E_F) * e, e, lqc);
            dadd[q] = fmaf((-16.0f * L2E_F) * z, z, base);
        }

        // ---- detection: wave 0 polls own direction's 128 one-line sentinels ----
        if (wave == 0) {
            const int* s0 = mysent + lane * SSTRIDE;
            const int* s1 = mysent + (lane + 64) * SSTRIDE;
            for (;;) {
                int v0 = sload(s0);
                int v1 = sload(s1);
                if (__all(min(v0, v1) >= need)) break;
                __builtin_amdgcn_s_sleep(1);
            }
            __hip_atomic_store(&ldsflag, need, __ATOMIC_RELEASE,
                               __HIP_MEMORY_SCOPE_WORKGROUP);
        } else {
            while (__hip_atomic_load(&ldsflag, __ATOMIC_ACQUIRE,
                                     __HIP_MEMORY_SCOPE_WORKGROUP) < need)
                __builtin_amdgcn_s_sleep(1);
        }

        // ---- one-shot parallel read of the message row + LDS stage ----
        const float* mrow = mybuf + par * K;
        float rv[QS];
        #pragma unroll
        for (int q = 0; q < QS; ++q) rv[q] = aload4(&mrow[tid + q * NTHREADS]);
        #pragma unroll
        for (int q = 0; q < QS; ++q)
            shzD[par][tid + q * NTHREADS] = make_float2(zloc[q], rv[q] + dadd[q]);
        __syncthreads();   // barrier A: stage ready

        // ---- this wave's 2 columns: max pass + exp2 pass over reg'd tiles ----
        const float4* shp = (const float4*)&shzD[par][0];
        float2 zcA = lzc[town][2 * wave];
        float2 zcB = lzc[town][2 * wave + 1];
        float4 fr[16];
        #pragma unroll
        for (int i = 0; i < 16; ++i) fr[i] = shp[lane + (i << 6)];
        float m0 = -INFINITY, m1 = -INFINITY;
        #pragma unroll
        for (int i = 0; i < 16; ++i) {
            m0 = fmaxf(m0, fmaxf(fmaf(zcA.x, fr[i].x, fr[i].y),
                                 fmaf(zcA.x, fr[i].z, fr[i].w)));
            m1 = fmaxf(m1, fmaxf(fmaf(zcB.x, fr[i].x, fr[i].y),
                                 fmaf(zcB.x, fr[i].z, fr[i].w)));
        }
        #pragma unroll
        for (int off = 32; off >= 1; off >>= 1) {
            m0 = fmaxf(m0, __shfl_xor(m0, off, 64));
            m1 = fmaxf(m1, __shfl_xor(m1, off, 64));
        }
        float s0 = 0.0f, s1 = 0.0f;
        #pragma unroll
        for (int i = 0; i < 16; ++i) {
            s0 += EXP2F(fmaf(zcA.x, fr[i].x, fr[i].y) - m0);
            s0 += EXP2F(fmaf(zcA.x, fr[i].z, fr[i].w) - m0);
            s1 += EXP2F(fmaf(zcB.x, fr[i].x, fr[i].y) - m1);
            s1 += EXP2F(fmaf(zcB.x, fr[i].z, fr[i].w) - m1);
        }
        #pragma unroll
        for (int off = 32; off >= 1; off >>= 1) {
            s0 += __shfl_xor(s0, off, 64);
            s1 += __shfl_xor(s1, off, 64);
        }
        if (lane < 2) {
            float mm = lane ? m1 : m0;
            float sv = lane ? s1 : s0;
            float cm = lane ? zcB.y : zcA.y;
            astore4(&mybuf[(par ^ 1) * K + col0 + 2 * wave + lane],
                    cm + mm + LOG2F(sv));
        }

        // ---- NO barrier B: per-wave drain + LDS pubcnt; 8th wave fires ----
        asm volatile("s_waitcnt vmcnt(0)" ::: "memory");   // own publish at MALL
        if (lane == 0) {
            int old = __hip_atomic_fetch_add(&pubcnt[par], 1, __ATOMIC_ACQ_REL,
                                             __HIP_MEMORY_SCOPE_WORKGROUP);
            if (old == ((p >> 1) + 1) * 8 - 1)   // 8th publisher of this use
                sstore(&mysent[lb * SSTRIDE], p + 2);
        }
    }

    // ---- join: out = lse_j(r_16[j] + c_16[j]) - lnK, block 0 only ----
    if (b == 0) {
        for (;;) {   // one-time poll of both directions, all waves
            int f0 = sload(&fsent[lane * SSTRIDE]);
            int f1 = sload(&fsent[(lane + 64) * SSTRIDE]);
            int g0 = sload(&bsent[lane * SSTRIDE]);
            int g1 = sload(&bsent[(lane + 64) * SSTRIDE]);
            bool ok = (min(f0, f1) >= 17) && (min(g0, g1) >= 16);
            if (__all(ok)) break;
            __builtin_amdgcn_s_sleep(1);
        }
        // r_16: fbuf parity 0 (last fwd step p=15 -> par^1 = 0)
        // c_16: bbuf parity 1 (last bwd step p=14 -> par^1 = 1)
        float vals[QS];
        float m = -INFINITY;
        #pragma unroll
        for (int q = 0; q < QS; ++q) {
            int j = tid + q * NTHREADS;
            float v = aload4(&fbuf[j]) + aload4(&bbuf[K + j]);   // log2 domain
            vals[q] = v;
            m = fmaxf(m, v);
        }
        red[tid] = m; __syncthreads();
        for (int off = NTHREADS / 2; off >= 1; off >>= 1) {
            if (tid < off) red[tid] = fmaxf(red[tid], red[tid + off]);
            __syncthreads();
        }
        m = red[0]; __syncthreads();
        float ssum = 0.0f;
        #pragma unroll
        for (int q = 0; q < QS; ++q) ssum += EXP2F(vals[q] - m);
        red[tid] = ssum; __syncthreads();
        for (int off = NTHREADS / 2; off >= 1; off >>= 1) {
            if (tid < off) red[tid] += red[tid + off];
            __syncthreads();
        }
        if (tid == 0) out[0] = LN2_F * (m + LOG2F(red[0]) - 11.0f);
    }
}

extern "C" void kernel_launch(void* const* d_in, const int* in_sizes, int n_in,
                              void* d_out, int out_size, void* d_ws, size_t ws_size,
                              hipStream_t stream) {
    const float* means    = (const float*)d_in[0];
    const float* log_stds = (const float*)d_in[1];
    const float* eps      = (const float*)d_in[2];
    float* out = (float*)d_out;

    float* fbuf = (float*)d_ws;                 // 2*K fwd rho ping-pong (16 KB)
    float* bbuf = fbuf + 2 * K;                 // 2*K bwd rho ping-pong (16 KB)
    int*   fsent = (int*)(bbuf + 2 * K);        // 128 fwd sentinels, 128 B apart (16 KB)
    int*   bsent = fsent + 128 * SSTRIDE;       // 128 bwd sentinels, 128 B apart (16 KB)

    fused_kernel<<<NBLOCKS, NTHREADS, 0, stream>>>(
        means, log_stds, eps, fbuf, bbuf, fsent, bsent, out);
}

// Round 19
// 112.934 us; speedup vs baseline: 1.0857x; 1.0857x over previous
//
#include <hip/hip_runtime.h>
#include <math.h>

#define T 32
#define K 2048
#define NBLOCKS 256
#define NTHREADS 512
#define HB 128                          // blocks per direction
#define CPB 16                          // columns per block (2 per wave)
#define QS 4                            // K / NTHREADS slots per thread
#define SSTRIDE 32                      // ints: 128 B -> one MALL line per sentinel
#define L2E_F 1.4426950408889634f       // log2(e)
#define LN2_F 0.6931471805599453f
#define LOG2PI_F 1.8378770664093453f
#define SP_F     0.17677669529663687f   // sqrt(1/32)
#define LOG_SP_F (-1.7328679513998633f) // ln(sqrt(1/32))
#define CNORM_F  (-(LOG_SP_F) - 0.5f * LOG2PI_F)   // -ln(sp) - 0.5 ln2pi

#if __has_builtin(__builtin_amdgcn_exp2f)
#define EXP2F(x) __builtin_amdgcn_exp2f(x)
#else
#define EXP2F(x) exp2f(x)
#endif
#if __has_builtin(__builtin_amdgcn_logf)
#define LOG2F(x) __builtin_amdgcn_logf(x)
#else
#define LOG2F(x) log2f(x)
#endif

// ALL global sync traffic is relaxed agent-scope atomics (write-through to
// the MALL, bypassing non-coherent per-XCD L2s). NO agent-scope
// release/acquire anywhere (R2/R7: ~15us/step of L2 cache maintenance).
// Producer ordering (data before sentinel) = __syncthreads' per-wave vmcnt
// drain before s_barrier.
__device__ __forceinline__ float aload4(const float* p) {
    return __hip_atomic_load(p, __ATOMIC_RELAXED, __HIP_MEMORY_SCOPE_AGENT);
}
__device__ __forceinline__ void astore4(float* p, float v) {
    __hip_atomic_store(p, v, __ATOMIC_RELAXED, __HIP_MEMORY_SCOPE_AGENT);
}
__device__ __forceinline__ int sload(const int* p) {
    return __hip_atomic_load(p, __ATOMIC_RELAXED, __HIP_MEMORY_SCOPE_AGENT);
}
__device__ __forceinline__ void sstore(int* p, int v) {
    __hip_atomic_store(p, v, __ATOMIC_RELAXED, __HIP_MEMORY_SCOPE_AGENT);
}

// CHAMPION (R15, 61.7us kernel): bidirectional meet-in-the-middle chain
// with sentinel-gated one-shot reads. Every structural element was
// falsified in isolation (R14/R16/R17/R18: cols-per-wave, block shape,
// speculative reads, barrier-B removal all regress; R9-R13: packed
// sentinels, all-wave polling, per-wave message polling, LDS flag
// machinery all regress; R2/R7: any agent-scope release costs ~15us/step).
//
// Blocks 0..127 run the FORWARD chain (r_1..r_16), blocks 128..255 the
// BACKWARD chain (c_30..c_16 seeded by the likelihood c_31);
// out = lse_j(r_16[j]+c_16[j]) - lnK. 16-step critical path. Per
// direction: 128 one-line (128B-spread) sentinels — spread beats packed
// because same-line agent-scope accesses serialize at the MALL — ONE
// polling wave per block, LDS-flag handoff (workgroup scope,
// lgkmcnt-only), parallel one-shot read of the 2048-float message row,
// two plain block barriers. Signed sentinels 1..17: the 0xAAAAAAAA
// poison is negative, never satisfies >=, so no init kernel. Ping-pong
// safety: advancing to step p+2 requires observing all sentinels >= p+1,
// hence every block consumed step p — rows are never overwritten while
// readable. Chain state carried in log2 domain (exp2/log2 native ops,
// log2(K) = 11 exactly; 0.5/sp^2 = 16 exactly).
__global__ __launch_bounds__(NTHREADS) void fused_kernel(
    const float* __restrict__ means, const float* __restrict__ log_stds,
    const float* __restrict__ eps, float* __restrict__ fbuf,
    float* __restrict__ bbuf, int* __restrict__ fsent, int* __restrict__ bsent,
    float* __restrict__ out)
{
    __shared__ float2 shzD[2][K];    // 32 KB: (z_j, D_j) staging, parity dbuf
    __shared__ float2 lzc[T][CPB];   // own cols: (32*L2E*z, cm2 const)
    __shared__ float smu[T], sstd[T], slq2[T];
    __shared__ float red[NTHREADS];
    __shared__ int ldsflag;

    const int tid  = threadIdx.x;
    const int b    = blockIdx.x;
    const bool fwd = (b < HB);
    const int lb   = fwd ? b : b - HB;
    const int col0 = lb * CPB;

    if (tid == 0) ldsflag = 0;

    // ---- setup: thread (t = tid>>4, dcol = tid&15) handles (t, col0+dcol) ----
    {
        int t = tid >> 4, dcol = tid & 15;
        float mu = means[t];
        float st = expf(log_stds[t]);
        if (dcol == 0) {
            smu[t] = mu; sstd[t] = st;
            slq2[t] = L2E_F * (logf(st) + 0.5f * LOG2PI_F);
        }
        float e = eps[t * K + col0 + dcol];
        float z = fmaf(st, e, mu);
        // (z-mu)/st == e exactly: log_q = -0.5 e^2 - ln(st) - 0.5 ln2pi
        float log_q = fmaf(-0.5f * e, e, -logf(st) - 0.5f * LOG2PI_F);
        float tz2 = (32.0f * L2E_F) * z;
        if (fwd) {
            float cm2 = fmaf((-16.0f * L2E_F) * z, z,
                             L2E_F * (CNORM_F - log_q)) - 11.0f;   // log2K = 11
            lzc[t][dcol] = make_float2(tz2, cm2);
            if (t == 0) {   // seed r_0, parity 0
                float r0 = fmaf(-16.0f * z, z, CNORM_F) - log_q;
                astore4(&fbuf[col0 + dcol], r0 * L2E_F);
            }
        } else {
            float cm2 = fmaf((-16.0f * L2E_F) * z, z, L2E_F * CNORM_F) - 11.0f;
            lzc[t][dcol] = make_float2(tz2, cm2);
            if (t == T - 1) {   // seed c_31 = likelihood, parity 0
                float d = 0.5f - z;
                float c31 = fmaf(-0.5f * d, d, -0.5f * LOG2PI_F);
                astore4(&bbuf[col0 + dcol], c31 * L2E_F);
            }
        }
    }
    __syncthreads();               // drains seed stores (vmcnt) + LDS init
    int* mysent = fwd ? fsent : bsent;
    if (tid == 0) sstore(&mysent[lb * SSTRIDE], 1);

    const int lane = tid & 63;
    const int wave = tid >> 6;     // 0..7: columns 2w, 2w+1
    float* mybuf = fwd ? fbuf : bbuf;
    const int nstep = fwd ? 16 : 15;

    for (int p = 0; p < nstep; ++p) {
        const int par  = p & 1;
        const int need = p + 1;
        const int tin  = fwd ? p : 31 - p;
        const int town = fwd ? p + 1 : 30 - p;
        const float mu_i  = smu[tin];
        const float std_i = sstd[tin];
        const float lqc   = slq2[tin];
        const float* erow = eps + tin * K;

        // ---- pre-poll: z + D-addend for own QS slots (r-independent) ----
        float zloc[QS], dadd[QS];
        #pragma unroll
        for (int q = 0; q < QS; ++q) {
            float e = erow[tid + q * NTHREADS];
            float z = fmaf(std_i, e, mu_i);
            zloc[q] = z;
            float base = fwd ? 0.0f : fmaf((0.5f * L2E_F) * e, e, lqc);
            dadd[q] = fmaf((-16.0f * L2E_F) * z, z, base);
        }

        // ---- detection: wave 0 polls own direction's 128 one-line sentinels ----
        if (wave == 0) {
            const int* s0 = mysent + lane * SSTRIDE;
            const int* s1 = mysent + (lane + 64) * SSTRIDE;
            for (;;) {
                int v0 = sload(s0);
                int v1 = sload(s1);
                if (__all(min(v0, v1) >= need)) break;
                __builtin_amdgcn_s_sleep(1);
            }
            __hip_atomic_store(&ldsflag, need, __ATOMIC_RELEASE,
                               __HIP_MEMORY_SCOPE_WORKGROUP);
        } else {
            while (__hip_atomic_load(&ldsflag, __ATOMIC_ACQUIRE,
                                     __HIP_MEMORY_SCOPE_WORKGROUP) < need)
                __builtin_amdgcn_s_sleep(1);
        }

        // ---- one-shot parallel read of the message row + LDS stage ----
        const float* mrow = mybuf + par * K;
        float rv[QS];
        #pragma unroll
        for (int q = 0; q < QS; ++q) rv[q] = aload4(&mrow[tid + q * NTHREADS]);
        #pragma unroll
        for (int q = 0; q < QS; ++q)
            shzD[par][tid + q * NTHREADS] = make_float2(zloc[q], rv[q] + dadd[q]);
        __syncthreads();   // barrier A: stage ready

        // ---- this wave's 2 columns: max pass + exp2 pass over reg'd tiles ----
        const float4* shp = (const float4*)&shzD[par][0];
        float2 zcA = lzc[town][2 * wave];
        float2 zcB = lzc[town][2 * wave + 1];
        float4 fr[16];
        #pragma unroll
        for (int i = 0; i < 16; ++i) fr[i] = shp[lane + (i << 6)];
        float m0 = -INFINITY, m1 = -INFINITY;
        #pragma unroll
        for (int i = 0; i < 16; ++i) {
            m0 = fmaxf(m0, fmaxf(fmaf(zcA.x, fr[i].x, fr[i].y),
                                 fmaf(zcA.x, fr[i].z, fr[i].w)));
            m1 = fmaxf(m1, fmaxf(fmaf(zcB.x, fr[i].x, fr[i].y),
                                 fmaf(zcB.x, fr[i].z, fr[i].w)));
        }
        #pragma unroll
        for (int off = 32; off >= 1; off >>= 1) {
            m0 = fmaxf(m0, __shfl_xor(m0, off, 64));
            m1 = fmaxf(m1, __shfl_xor(m1, off, 64));
        }
        float s0 = 0.0f, s1 = 0.0f;
        #pragma unroll
        for (int i = 0; i < 16; ++i) {
            s0 += EXP2F(fmaf(zcA.x, fr[i].x, fr[i].y) - m0);
            s0 += EXP2F(fmaf(zcA.x, fr[i].z, fr[i].w) - m0);
            s1 += EXP2F(fmaf(zcB.x, fr[i].x, fr[i].y) - m1);
            s1 += EXP2F(fmaf(zcB.x, fr[i].z, fr[i].w) - m1);
        }
        #pragma unroll
        for (int off = 32; off >= 1; off >>= 1) {
            s0 += __shfl_xor(s0, off, 64);
            s1 += __shfl_xor(s1, off, 64);
        }
        if (lane < 2) {
            float mm = lane ? m1 : m0;
            float sv = lane ? s1 : s0;
            float cm = lane ? zcB.y : zcA.y;
            astore4(&mybuf[(par ^ 1) * K + col0 + 2 * wave + lane],
                    cm + mm + LOG2F(sv));
        }
        // barrier B drains every wave's publish (vmcnt) before s_barrier;
        // only then this block's sentinel advances.
        __syncthreads();
        if (tid == 0) sstore(&mysent[lb * SSTRIDE], p + 2);
    }

    // ---- join: out = lse_j(r_16[j] + c_16[j]) - lnK, block 0 only ----
    if (b == 0) {
        for (;;) {   // one-time poll of both directions, all waves
            int f0 = sload(&fsent[lane * SSTRIDE]);
            int f1 = sload(&fsent[(lane + 64) * SSTRIDE]);
            int g0 = sload(&bsent[lane * SSTRIDE]);
            int g1 = sload(&bsent[(lane + 64) * SSTRIDE]);
            bool ok = (min(f0, f1) >= 17) && (min(g0, g1) >= 16);
            if (__all(ok)) break;
            __builtin_amdgcn_s_sleep(1);
        }
        // r_16: fbuf parity 0 (last fwd step p=15 -> par^1 = 0)
        // c_16: bbuf parity 1 (last bwd step p=14 -> par^1 = 1)
        float vals[QS];
        float m = -INFINITY;
        #pragma unroll
        for (int q = 0; q < QS; ++q) {
            int j = tid + q * NTHREADS;
            float v = aload4(&fbuf[j]) + aload4(&bbuf[K + j]);   // log2 domain
            vals[q] = v;
            m = fmaxf(m, v);
        }
        red[tid] = m; __syncthreads();
        for (int off = NTHREADS / 2; off >= 1; off >>= 1) {
            if (tid < off) red[tid] = fmaxf(red[tid], red[tid + off]);
            __syncthreads();
        }
        m = red[0]; __syncthreads();
        float ssum = 0.0f;
        #pragma unroll
        for (int q = 0; q < QS; ++q) ssum += EXP2F(vals[q] - m);
        red[tid] = ssum; __syncthreads();
        for (int off = NTHREADS / 2; off >= 1; off >>= 1) {
            if (tid < off) red[tid] += red[tid + off];
            __syncthreads();
        }
        if (tid == 0) out[0] = LN2_F * (m + LOG2F(red[0]) - 11.0f);
    }
}

extern "C" void kernel_launch(void* const* d_in, const int* in_sizes, int n_in,
                              void* d_out, int out_size, void* d_ws, size_t ws_size,
                              hipStream_t stream) {
    const float* means    = (const float*)d_in[0];
    const float* log_stds = (const float*)d_in[1];
    const float* eps      = (const float*)d_in[2];
    float* out = (float*)d_out;

    float* fbuf = (float*)d_ws;                 // 2*K fwd rho ping-pong (16 KB)
    float* bbuf = fbuf + 2 * K;                 // 2*K bwd rho ping-pong (16 KB)
    int*   fsent = (int*)(bbuf + 2 * K);        // 128 fwd sentinels, 128 B apart (16 KB)
    int*   bsent = fsent + 128 * SSTRIDE;       // 128 bwd sentinels, 128 B apart (16 KB)

    fused_kernel<<<NBLOCKS, NTHREADS, 0, stream>>>(
        means, log_stds, eps, fbuf, bbuf, fsent, bsent, out);
}